// Round 11
// baseline (17.886 us; speedup 1.0000x reference)
//
#include <hip/hip_runtime.h>
#include <hip/hip_bf16.h>

typedef __attribute__((ext_vector_type(8))) short bf16x8;   // MFMA A/B frag (8 bf16)
typedef __attribute__((ext_vector_type(4))) float f32x4;    // MFMA C/D frag
typedef __attribute__((ext_vector_type(4))) unsigned int u32x4;

constexpr int NPTS = 4096;
constexpr int HH = 256;
constexpr int WW = 256;
constexpr int PSEG  = 256;   // per-wave primary segment (mean ~91 of 512 scanned)
constexpr int CWCAP = 192;   // per-wave tile list cap (mean ~110, +8 sigma)
constexpr int CCAPW = 224;   // CWCAP + pad room (CWCAP already 32-mult)

// S = sqrt(INV_VAR * log2(e)); exp(-INV_VAR*d^2) = exp2(-(S*d)^2)
#define SCALE_S 0.56621453f
// cutoff: dropped-point contribution <= 1e5*2^-32 = 2.3e-5 each
#define DCUT 10.0f

// HW packed f32->bf16 (RNE), D.lo = bf16(lo), D.hi = bf16(hi)
__device__ inline unsigned cvtpk(float lo, float hi) {
    unsigned r;
    asm("v_cvt_pk_bf16_f32 %0, %1, %2" : "=v"(r) : "v"(lo), "v"(hi));
    return r;
}

// Block = 8 waves covering 64x64 (4x2 tiles of 16x32); each WAVE owns one tile.
// Grid 512 x 512thr -> 16 waves/CU (4/SIMD). Dedup'd gen + 2x latency hiding.
__global__ __launch_bounds__(512, 4) void soft_raster_kernel(
    const float* __restrict__ p2d,   // (32, 4096, 2)
    const float* __restrict__ pz,    // (32, 4096)
    float* __restrict__ out)         // (32, 256, 256)
{
    const int bk  = blockIdx.z;
    const int tm  = blockIdx.y * 64;
    const int tn  = blockIdx.x * 64;
    const int tid = threadIdx.x;

    __shared__ __align__(16) float sxs[8 * PSEG], sys[8 * PSEG], szi[8 * PSEG];
    __shared__ __align__(16) float cxs[8 * CCAPW], cys[8 * CCAPW], czi[8 * CCAPW];
    __shared__ int scnt[8];

    const int wid  = tid >> 6;                 // wave 0..7
    const int lane = tid & 63;
    const int tmw  = tm + ((wid >> 1) << 4);   // tile row base (16-row tile)
    const int tnw  = tn + ((wid & 1) << 5);    // tile col base (32-col tile)
    const int g    = lane >> 4;                // k-group 0..3
    const int r    = lane & 15;

    const size_t pbase = (size_t)bk * NPTS;
    const float4* __restrict__ pxy4 =
        reinterpret_cast<const float4*>(p2d + 2 * pbase);   // 2 points / float4
    const float2* __restrict__ pz2 =
        reinterpret_cast<const float2*>(pz + pbase);

    const unsigned long long maskl = (1ull << lane) - 1ull;

    // ---- primary scan: wave owns 512 points; prefetch all, then ballot chain ----
    const float Xlo = (float)tn - DCUT, Xhi = (float)(tn + 63) + DCUT;
    const float Ylo = (float)tm - DCUT, Yhi = (float)(tm + 63) + DCUT;

    float4 P[4];
    float2 Z[4];
    #pragma unroll
    for (int it = 0; it < 4; ++it) P[it] = pxy4[(wid << 8) + (it << 6) + lane];
    #pragma unroll
    for (int it = 0; it < 4; ++it) Z[it] = pz2[(wid << 8) + (it << 6) + lane];

#define PSTEP(flag, xv, yv, zv)                                               \
    {                                                                         \
        unsigned long long b_ = __ballot(flag);                               \
        int p_ = base + __popcll(b_ & maskl);                                 \
        if ((flag) && p_ < PSEG) {                                            \
            const int s_ = (wid << 8) + p_;                                   \
            sxs[s_] = (xv) * SCALE_S;                                         \
            sys[s_] = (yv) * SCALE_S;                                         \
            szi[s_] = -__builtin_amdgcn_logf(fmaxf((zv), 1e-5f));             \
        }                                                                     \
        base += __popcll(b_);                                                 \
    }

    int base = 0;
    #pragma unroll
    for (int it = 0; it < 4; ++it) {
        const float4 p  = P[it];                 // x0 y0 x1 y1
        const float2 zz = Z[it];
        bool in0 = (p.x > Xlo) && (p.x < Xhi) && (p.y > Ylo) && (p.y < Yhi);
        bool in1 = (p.z > Xlo) && (p.z < Xhi) && (p.w > Ylo) && (p.w < Yhi);
        PSTEP(in0, p.x, p.y, zz.x);
        PSTEP(in1, p.z, p.w, zz.y);
    }
#undef PSTEP
    if (lane == 0) scnt[wid] = (base < PSEG) ? base : PSEG;
    __syncthreads();   // the only block barrier

    // ---- secondary filter: this wave's 36x52 window, 2 segments per round ----
    const float xlo = ((float)tnw - DCUT) * SCALE_S;
    const float xhi = ((float)(tnw + 31) + DCUT) * SCALE_S;
    const float ylo = ((float)tmw - DCUT) * SCALE_S;
    const float yhi = ((float)(tmw + 15) + DCUT) * SCALE_S;
    float* __restrict__ wxs = cxs + wid * CCAPW;
    float* __restrict__ wys = cys + wid * CCAPW;
    float* __restrict__ wzi = czi + wid * CCAPW;

#define FSTEP(flag, xv, yv, zv)                                               \
    {                                                                         \
        unsigned long long b_ = __ballot(flag);                               \
        int p_ = cw + __popcll(b_ & maskl);                                   \
        if ((flag) && p_ < CWCAP) { wxs[p_] = (xv); wys[p_] = (yv); wzi[p_] = (zv); } \
        cw += __popcll(b_);                                                   \
    }

    int cw = 0;
    const int jb = lane << 2;       // this lane's 4 candidate slots per segment
    #pragma unroll
    for (int s2 = 0; s2 < 4; ++s2) {
        const int sa = s2 << 1, sb = sa | 1;
        const int csa = scnt[sa], csb = scnt[sb];
        const float4 xa = *reinterpret_cast<const float4*>(&sxs[(sa << 8) + jb]);
        const float4 ya = *reinterpret_cast<const float4*>(&sys[(sa << 8) + jb]);
        const float4 za = *reinterpret_cast<const float4*>(&szi[(sa << 8) + jb]);
        const float4 xb = *reinterpret_cast<const float4*>(&sxs[(sb << 8) + jb]);
        const float4 yb = *reinterpret_cast<const float4*>(&sys[(sb << 8) + jb]);
        const float4 zb = *reinterpret_cast<const float4*>(&szi[(sb << 8) + jb]);
        bool a0 = (jb + 0 < csa) && (xa.x > xlo) && (xa.x < xhi) && (ya.x > ylo) && (ya.x < yhi);
        bool a1 = (jb + 1 < csa) && (xa.y > xlo) && (xa.y < xhi) && (ya.y > ylo) && (ya.y < yhi);
        bool a2 = (jb + 2 < csa) && (xa.z > xlo) && (xa.z < xhi) && (ya.z > ylo) && (ya.z < yhi);
        bool a3 = (jb + 3 < csa) && (xa.w > xlo) && (xa.w < xhi) && (ya.w > ylo) && (ya.w < yhi);
        bool b0 = (jb + 0 < csb) && (xb.x > xlo) && (xb.x < xhi) && (yb.x > ylo) && (yb.x < yhi);
        bool b1 = (jb + 1 < csb) && (xb.y > xlo) && (xb.y < xhi) && (yb.y > ylo) && (yb.y < yhi);
        bool b2 = (jb + 2 < csb) && (xb.z > xlo) && (xb.z < xhi) && (yb.z > ylo) && (yb.z < yhi);
        bool b3 = (jb + 3 < csb) && (xb.w > xlo) && (xb.w < xhi) && (yb.w > ylo) && (yb.w < yhi);
        FSTEP(a0, xa.x, ya.x, za.x);
        FSTEP(a1, xa.y, ya.y, za.y);
        FSTEP(a2, xa.z, ya.z, za.z);
        FSTEP(a3, xa.w, ya.w, za.w);
        FSTEP(b0, xb.x, yb.x, zb.x);
        FSTEP(b1, xb.y, yb.y, zb.y);
        FSTEP(b2, xb.z, yb.z, zb.z);
        FSTEP(b3, xb.w, yb.w, zb.w);
    }
#undef FSTEP
    cw = (cw < CWCAP) ? cw : CWCAP;
    const int pw = (cw + 31) & ~31;          // pad to K-step multiple (<= CCAPW)
    for (int j = cw + lane; j < pw; j += 64) {
        wxs[j] = 0.f; wys[j] = 0.f; wzi[j] = -__builtin_inff();   // exact zeros
    }

    // ---- barrier-free main loop: register-direct, au x bu[2], 2 MFMA/step ----
    f32x4 acc[2] = {};
    const float qy  = (float)(tmw + r)      * SCALE_S;
    const float qx0 = (float)(tnw + r)      * SCALE_S;
    const float qx1 = (float)(tnw + 16 + r) * SCALE_S;

    for (int k0 = 0; k0 < pw; k0 += 32) {
        const int kb = k0 + (g << 3);

        float4 y0 = *reinterpret_cast<const float4*>(&wys[kb]);
        float4 y1 = *reinterpret_cast<const float4*>(&wys[kb + 4]);
        float4 z0 = *reinterpret_cast<const float4*>(&wzi[kb]);
        float4 z1 = *reinterpret_cast<const float4*>(&wzi[kb + 4]);
        float4 x0 = *reinterpret_cast<const float4*>(&wxs[kb]);
        float4 x1 = *reinterpret_cast<const float4*>(&wxs[kb + 4]);

        u32x4 au, bu[2];
        {
            float d;
            d = qy - y0.x; const float a0 = __builtin_amdgcn_exp2f(fmaf(d, -d, z0.x));
            d = qy - y0.y; const float a1 = __builtin_amdgcn_exp2f(fmaf(d, -d, z0.y));
            d = qy - y0.z; const float a2 = __builtin_amdgcn_exp2f(fmaf(d, -d, z0.z));
            d = qy - y0.w; const float a3 = __builtin_amdgcn_exp2f(fmaf(d, -d, z0.w));
            d = qy - y1.x; const float a4 = __builtin_amdgcn_exp2f(fmaf(d, -d, z1.x));
            d = qy - y1.y; const float a5 = __builtin_amdgcn_exp2f(fmaf(d, -d, z1.y));
            d = qy - y1.z; const float a6 = __builtin_amdgcn_exp2f(fmaf(d, -d, z1.z));
            d = qy - y1.w; const float a7 = __builtin_amdgcn_exp2f(fmaf(d, -d, z1.w));
            au[0] = cvtpk(a0, a1); au[1] = cvtpk(a2, a3);
            au[2] = cvtpk(a4, a5); au[3] = cvtpk(a6, a7);
        }
        #pragma unroll
        for (int ni = 0; ni < 2; ++ni) {
            const float qx = ni ? qx1 : qx0;
            float d;
            d = qx - x0.x; const float b0 = __builtin_amdgcn_exp2f(-(d * d));
            d = qx - x0.y; const float b1 = __builtin_amdgcn_exp2f(-(d * d));
            d = qx - x0.z; const float b2 = __builtin_amdgcn_exp2f(-(d * d));
            d = qx - x0.w; const float b3 = __builtin_amdgcn_exp2f(-(d * d));
            d = qx - x1.x; const float b4 = __builtin_amdgcn_exp2f(-(d * d));
            d = qx - x1.y; const float b5 = __builtin_amdgcn_exp2f(-(d * d));
            d = qx - x1.z; const float b6 = __builtin_amdgcn_exp2f(-(d * d));
            d = qx - x1.w; const float b7 = __builtin_amdgcn_exp2f(-(d * d));
            bu[ni][0] = cvtpk(b0, b1); bu[ni][1] = cvtpk(b2, b3);
            bu[ni][2] = cvtpk(b4, b5); bu[ni][3] = cvtpk(b6, b7);
        }
        #pragma unroll
        for (int ni = 0; ni < 2; ++ni)
            acc[ni] = __builtin_amdgcn_mfma_f32_16x16x32_bf16(
                __builtin_bit_cast(bf16x8, au),
                __builtin_bit_cast(bf16x8, bu[ni]), acc[ni], 0, 0, 0);
    }

    // ---- epilogue: C/D layout col=lane&15, row=4*(lane>>4)+reg ----
    float* obase = out + (size_t)bk * (HH * WW);
    const int row0 = tmw + (g << 2);
    #pragma unroll
    for (int ni = 0; ni < 2; ++ni) {
        const int col = tnw + (ni << 4) + r;
        #pragma unroll
        for (int j = 0; j < 4; ++j)
            obase[(size_t)(row0 + j) * WW + col] = acc[ni][j];
    }
}

extern "C" void kernel_launch(void* const* d_in, const int* in_sizes, int n_in,
                              void* d_out, int out_size, void* d_ws, size_t ws_size,
                              hipStream_t stream) {
    const float* p2d = (const float*)d_in[0];
    const float* pz  = (const float*)d_in[1];
    float* out       = (float*)d_out;
    const int nbk    = in_sizes[1] / NPTS;   // B*K = 32
    dim3 grid(WW / 64, HH / 64, nbk);        // (4, 4, 32) = 512 WGs
    dim3 block(512);
    hipLaunchKernelGGL(soft_raster_kernel, grid, block, 0, stream, p2d, pz, out);
}

// Round 12
// 15.221 us; speedup vs baseline: 1.1751x; 1.1751x over previous
//
#include <hip/hip_runtime.h>
#include <hip/hip_bf16.h>

typedef __attribute__((ext_vector_type(8))) short bf16x8;   // MFMA A/B frag (8 bf16)
typedef __attribute__((ext_vector_type(4))) float f32x4;    // MFMA C/D frag
typedef __attribute__((ext_vector_type(4))) unsigned int u32x4;

constexpr int NPTS = 4096;
constexpr int HH = 256;
constexpr int WW = 256;
constexpr int PSEG = 256;    // per-wave primary segment cap (mean ~104)
constexpr int CCAPW = 288;   // per-wave compact region (cap 256 + pad to 32)

// S = sqrt(INV_VAR * log2(e)); exp(-INV_VAR*d^2) = exp2(-(S*d)^2)
#define SCALE_S 0.56621453f
// cutoff: dropped-point contribution <= 1e5*2^-32 = 2.3e-5 each
#define DCUT 10.0f

// HW packed f32->bf16 (RNE), D.lo = bf16(lo), D.hi = bf16(hi)
__device__ inline unsigned cvtpk(float lo, float hi) {
    unsigned r;
    asm("v_cvt_pk_bf16_f32 %0, %1, %2" : "=v"(r) : "v"(lo), "v"(hi));
    return r;
}

// Block = 4 waves covering 64x64; each WAVE owns one 32x32 tile (dedup'd gen).
// Grid 512; one barrier; scan stores x,y,idx only -- z gathered post-hoc for
// accepted points (masked transcendentals removed from the ballot chain).
__global__ __launch_bounds__(256, 2) void soft_raster_kernel(
    const float* __restrict__ p2d,   // (32, 4096, 2)
    const float* __restrict__ pz,    // (32, 4096)
    float* __restrict__ out)         // (32, 256, 256)
{
    const int bk  = blockIdx.z;
    const int tm  = blockIdx.y * 64;
    const int tn  = blockIdx.x * 64;
    const int tid = threadIdx.x;

    __shared__ __align__(16) float sxs[4 * PSEG], sys[4 * PSEG], szi[4 * PSEG];
    __shared__ unsigned short lkid[4 * PSEG];
    __shared__ __align__(16) float cxs[4 * CCAPW], cys[4 * CCAPW], czi[4 * CCAPW];
    __shared__ int scnt[4];

    const int wid  = tid >> 6;
    const int lane = tid & 63;
    const int tmw  = tm + ((wid >> 1) << 5);   // this wave's 32x32 tile
    const int tnw  = tn + ((wid & 1) << 5);
    const int g    = lane >> 4;                // k-group 0..3
    const int r    = lane & 15;

    const size_t pbase = (size_t)bk * NPTS;
    const float4* __restrict__ pxy4 =
        reinterpret_cast<const float4*>(p2d + 2 * pbase);   // 2 points / float4

    // ---- primary scan: prefetch point coords, ballot chain stores x,y,idx ----
    const float Xlo = (float)tn - DCUT, Xhi = (float)(tn + 63) + DCUT;
    const float Ylo = (float)tm - DCUT, Yhi = (float)(tm + 63) + DCUT;
    const unsigned long long maskl = (1ull << lane) - 1ull;

    float4 P[8];
    #pragma unroll
    for (int it = 0; it < 8; ++it) P[it] = pxy4[(wid << 9) + (it << 6) + lane];

#define PSTEP(flag, xv, yv, kidx)                                             \
    {                                                                         \
        unsigned long long b_ = __ballot(flag);                               \
        int p_ = base + __popcll(b_ & maskl);                                 \
        if ((flag) && p_ < PSEG) {                                            \
            const int s_ = (wid << 8) + p_;                                   \
            sxs[s_] = (xv) * SCALE_S;                                         \
            sys[s_] = (yv) * SCALE_S;                                         \
            lkid[s_] = (unsigned short)(kidx);                                \
        }                                                                     \
        base += __popcll(b_);                                                 \
    }

    int base = 0;
    #pragma unroll
    for (int it = 0; it < 8; ++it) {
        const float4 p = P[it];                         // x0 y0 x1 y1
        const int j4 = (wid << 9) + (it << 6) + lane;
        bool in0 = (p.x > Xlo) && (p.x < Xhi) && (p.y > Ylo) && (p.y < Yhi);
        bool in1 = (p.z > Xlo) && (p.z < Xhi) && (p.w > Ylo) && (p.w < Yhi);
        PSTEP(in0, p.x, p.y, 2 * j4);
        PSTEP(in1, p.z, p.w, 2 * j4 + 1);
    }
#undef PSTEP
    const int mycnt = (base < PSEG) ? base : PSEG;
    if (lane == 0) scnt[wid] = mycnt;

    // ---- deferred z-gather + log2, only for accepted points (~2/lane) ----
    for (int j = lane; j < mycnt; j += 64) {
        const int s  = (wid << 8) + j;
        const int kk = lkid[s];
        szi[s] = -__builtin_amdgcn_logf(fmaxf(pz[pbase + kk], 1e-5f));
    }
    __syncthreads();   // the only block barrier

    // ---- secondary filter: 4 points/lane, ONE iteration per segment ----
    const float xlo = ((float)tnw - DCUT) * SCALE_S;
    const float xhi = ((float)(tnw + 31) + DCUT) * SCALE_S;
    const float ylo = ((float)tmw - DCUT) * SCALE_S;
    const float yhi = ((float)(tmw + 31) + DCUT) * SCALE_S;
    float* __restrict__ wxs = cxs + wid * CCAPW;
    float* __restrict__ wys = cys + wid * CCAPW;
    float* __restrict__ wzi = czi + wid * CCAPW;

    int cw = 0;
    #pragma unroll
    for (int s = 0; s < 4; ++s) {
        const int cs = scnt[s];
        const int jb = lane << 2;     // this lane's 4 candidate slots
        const float4 x4 = *reinterpret_cast<const float4*>(&sxs[(s << 8) + jb]);
        const float4 y4 = *reinterpret_cast<const float4*>(&sys[(s << 8) + jb]);
        const float4 z4 = *reinterpret_cast<const float4*>(&szi[(s << 8) + jb]);
        bool i0 = (jb + 0 < cs) && (x4.x > xlo) && (x4.x < xhi) && (y4.x > ylo) && (y4.x < yhi);
        bool i1 = (jb + 1 < cs) && (x4.y > xlo) && (x4.y < xhi) && (y4.y > ylo) && (y4.y < yhi);
        bool i2 = (jb + 2 < cs) && (x4.z > xlo) && (x4.z < xhi) && (y4.z > ylo) && (y4.z < yhi);
        bool i3 = (jb + 3 < cs) && (x4.w > xlo) && (x4.w < xhi) && (y4.w > ylo) && (y4.w < yhi);
        unsigned long long b0 = __ballot(i0), b1 = __ballot(i1);
        unsigned long long b2 = __ballot(i2), b3 = __ballot(i3);
        const int c0 = __popcll(b0), c1 = __popcll(b1), c2 = __popcll(b2);
        int pos0 = cw + __popcll(b0 & maskl);
        int pos1 = cw + c0 + __popcll(b1 & maskl);
        int pos2 = cw + c0 + c1 + __popcll(b2 & maskl);
        int pos3 = cw + c0 + c1 + c2 + __popcll(b3 & maskl);
        if (i0 && pos0 < 256) { wxs[pos0] = x4.x; wys[pos0] = y4.x; wzi[pos0] = z4.x; }
        if (i1 && pos1 < 256) { wxs[pos1] = x4.y; wys[pos1] = y4.y; wzi[pos1] = z4.y; }
        if (i2 && pos2 < 256) { wxs[pos2] = x4.z; wys[pos2] = y4.z; wzi[pos2] = z4.z; }
        if (i3 && pos3 < 256) { wxs[pos3] = x4.w; wys[pos3] = y4.w; wzi[pos3] = z4.w; }
        cw += c0 + c1 + c2 + __popcll(b3);
    }
    cw = (cw < 256) ? cw : 256;
    const int pw = (cw + 31) & ~31;          // pad to K-step multiple
    for (int j = cw + lane; j < pw; j += 64) {
        wxs[j] = 0.f; wys[j] = 0.f; wzi[j] = -__builtin_inff();   // exact zeros
    }

    // ---- barrier-free main loop: wave-private, register-direct, 4 MFMA/step ----
    f32x4 acc[2][2] = {};
    const float qy0 = (float)(tmw + r)      * SCALE_S;
    const float qy1 = (float)(tmw + 16 + r) * SCALE_S;
    const float qx0 = (float)(tnw + r)      * SCALE_S;
    const float qx1 = (float)(tnw + 16 + r) * SCALE_S;

    for (int k0 = 0; k0 < pw; k0 += 32) {
        const int kb = k0 + (g << 3);

        float4 y0 = *reinterpret_cast<const float4*>(&wys[kb]);
        float4 y1 = *reinterpret_cast<const float4*>(&wys[kb + 4]);
        float4 z0 = *reinterpret_cast<const float4*>(&wzi[kb]);
        float4 z1 = *reinterpret_cast<const float4*>(&wzi[kb + 4]);
        float4 x0 = *reinterpret_cast<const float4*>(&wxs[kb]);
        float4 x1 = *reinterpret_cast<const float4*>(&wxs[kb + 4]);

        u32x4 au[2], bu[2];
        #pragma unroll
        for (int mi = 0; mi < 2; ++mi) {
            const float qy = mi ? qy1 : qy0;
            float d;
            d = qy - y0.x; const float a0 = __builtin_amdgcn_exp2f(fmaf(d, -d, z0.x));
            d = qy - y0.y; const float a1 = __builtin_amdgcn_exp2f(fmaf(d, -d, z0.y));
            d = qy - y0.z; const float a2 = __builtin_amdgcn_exp2f(fmaf(d, -d, z0.z));
            d = qy - y0.w; const float a3 = __builtin_amdgcn_exp2f(fmaf(d, -d, z0.w));
            d = qy - y1.x; const float a4 = __builtin_amdgcn_exp2f(fmaf(d, -d, z1.x));
            d = qy - y1.y; const float a5 = __builtin_amdgcn_exp2f(fmaf(d, -d, z1.y));
            d = qy - y1.z; const float a6 = __builtin_amdgcn_exp2f(fmaf(d, -d, z1.z));
            d = qy - y1.w; const float a7 = __builtin_amdgcn_exp2f(fmaf(d, -d, z1.w));
            au[mi][0] = cvtpk(a0, a1); au[mi][1] = cvtpk(a2, a3);
            au[mi][2] = cvtpk(a4, a5); au[mi][3] = cvtpk(a6, a7);
        }
        #pragma unroll
        for (int ni = 0; ni < 2; ++ni) {
            const float qx = ni ? qx1 : qx0;
            float d;
            d = qx - x0.x; const float b0 = __builtin_amdgcn_exp2f(-(d * d));
            d = qx - x0.y; const float b1 = __builtin_amdgcn_exp2f(-(d * d));
            d = qx - x0.z; const float b2 = __builtin_amdgcn_exp2f(-(d * d));
            d = qx - x0.w; const float b3 = __builtin_amdgcn_exp2f(-(d * d));
            d = qx - x1.x; const float b4 = __builtin_amdgcn_exp2f(-(d * d));
            d = qx - x1.y; const float b5 = __builtin_amdgcn_exp2f(-(d * d));
            d = qx - x1.z; const float b6 = __builtin_amdgcn_exp2f(-(d * d));
            d = qx - x1.w; const float b7 = __builtin_amdgcn_exp2f(-(d * d));
            bu[ni][0] = cvtpk(b0, b1); bu[ni][1] = cvtpk(b2, b3);
            bu[ni][2] = cvtpk(b4, b5); bu[ni][3] = cvtpk(b6, b7);
        }
        #pragma unroll
        for (int mi = 0; mi < 2; ++mi)
            #pragma unroll
            for (int ni = 0; ni < 2; ++ni)
                acc[mi][ni] = __builtin_amdgcn_mfma_f32_16x16x32_bf16(
                    __builtin_bit_cast(bf16x8, au[mi]),
                    __builtin_bit_cast(bf16x8, bu[ni]), acc[mi][ni], 0, 0, 0);
    }

    // ---- epilogue: C/D layout col=lane&15, row=4*(lane>>4)+reg ----
    float* obase = out + (size_t)bk * (HH * WW);
    #pragma unroll
    for (int mi = 0; mi < 2; ++mi) {
        #pragma unroll
        for (int ni = 0; ni < 2; ++ni) {
            const int col  = tnw + (ni << 4) + r;
            const int row0 = tmw + (mi << 4) + (g << 2);
            #pragma unroll
            for (int j = 0; j < 4; ++j)
                obase[(size_t)(row0 + j) * WW + col] = acc[mi][ni][j];
        }
    }
}

extern "C" void kernel_launch(void* const* d_in, const int* in_sizes, int n_in,
                              void* d_out, int out_size, void* d_ws, size_t ws_size,
                              hipStream_t stream) {
    const float* p2d = (const float*)d_in[0];
    const float* pz  = (const float*)d_in[1];
    float* out       = (float*)d_out;
    const int nbk    = in_sizes[1] / NPTS;   // B*K = 32
    dim3 grid(WW / 64, HH / 64, nbk);        // (4, 4, 32) = 512 WGs
    dim3 block(256);
    hipLaunchKernelGGL(soft_raster_kernel, grid, block, 0, stream, p2d, pz, out);
}